// Round 6
// baseline (285.792 us; speedup 1.0000x reference)
//
#include <hip/hip_runtime.h>
#include <hip/hip_cooperative_groups.h>

#define N_PIX 8192
#define C_DIM 128
#define TAU_INV_LOG2E 20.609929155556622f  // log2(e) / 0.07
#define EPS_DEN 1e-8f
#define NT_TILES 68                        // 4 classes each padded to x128 + tail -> 68 tiles
#define NT_ROWS (NT_TILES * 128)           // 8704
#define FAKE_ROWS (NT_ROWS - N_PIX)        // exactly 512 zero rows; each adds exp2(0)=1 to den

typedef unsigned short u16;
typedef __attribute__((ext_vector_type(8))) short short8;
typedef __attribute__((ext_vector_type(4))) float f32x4;

__device__ __forceinline__ u16 f2bf(float f) {
    unsigned u = __float_as_uint(f);
    return (u16)((u + 0x7fffu + ((u >> 16) & 1u)) >> 16);  // RNE
}

struct P1 {
    float tile[128][33];       // 128 ch x 32 hw, +1 pad  (16896 B)
    float sscale[32];
    int sdest[32];
    int chunkcnt[256][4];      // per-32-pixel-chunk class counts (4096 B)
    int pfx[256][4];           // exclusive prefix per chunk per class (4096 B)
    int tot[4];
};
struct P2 { u16 sA[128 * 128]; };   // XOR-swizzled A-tile, exactly 32768 B
struct P3 { float part[4]; };
union SMem { P1 p1; P2 p2; P3 p3; };  // 32768 B -> 2 blocks/CU even under 64KiB accounting

// meta layout (ints): [8] ticket (fallback), [12..15] pad_count[4], [16..16+NT_TILES) tile_class

// ---- Phase 1: fused L2-normalize + transpose + (target) inline counting-sort scatter ----
__device__ __forceinline__ void phase1(SMem& sm, int bid, int t,
                                       const float* __restrict__ input,
                                       const float* __restrict__ target,
                                       const int* __restrict__ tseg,
                                       int* __restrict__ meta,
                                       u16* __restrict__ ni_bf,
                                       u16* __restrict__ nt_sorted,
                                       float* __restrict__ den,
                                       float* __restrict__ nom) {
    int lane = t & 63, w = t >> 6;
    int arr = bid >> 8;              // 0 = input, 1 = target
    int u = bid & 255;
    int bb = u >> 7;
    int hw0 = (u & 127) * 32;
    const float* src = (arr ? target : input) + bb * (C_DIM * 4096);

    if (arr == 0) {
        if (t < 32) den[u * 32 + t] = 0.f;
        else if (t < 64) nom[u * 32 + (t - 32)] = 0.f;
        if (bid == 0 && t == 64) meta[8] = 0;   // ticket for fallback path
    }

    // load 128ch x 32hw fp32 tile (coalesced along hw)
    int c8 = t >> 5, hwl = t & 31;
#pragma unroll
    for (int i = 0; i < 16; ++i) {
        int c = i * 8 + c8;
        sm.p1.tile[c][hwl] = src[c * 4096 + hw0 + hwl];
    }

    int ps[5] = {0, 0, 0, 0, 0};
    int padc[4] = {0, 0, 0, 0};
    if (arr) {
        // redundant per-block histogram of full tseg (32 KB, L2-hot)
        int c0 = 0, c1 = 0, c2 = 0, c3 = 0;
        const int4* ts4 = (const int4*)tseg;
#pragma unroll
        for (int j = 0; j < 8; ++j) {
            int4 x = ts4[t * 8 + j];
            c0 += (x.x == 0) + (x.y == 0) + (x.z == 0) + (x.w == 0);
            c1 += (x.x == 1) + (x.y == 1) + (x.z == 1) + (x.w == 1);
            c2 += (x.x == 2) + (x.y == 2) + (x.z == 2) + (x.w == 2);
            c3 += (x.x == 3) + (x.y == 3) + (x.z == 3) + (x.w == 3);
        }
        sm.p1.chunkcnt[t][0] = c0; sm.p1.chunkcnt[t][1] = c1;
        sm.p1.chunkcnt[t][2] = c2; sm.p1.chunkcnt[t][3] = c3;
    }
    __syncthreads();

    if (arr) {
        // scan: wave w handles class w across 256 chunks
        int c = w;
        int vv[4];
#pragma unroll
        for (int j = 0; j < 4; ++j) vv[j] = sm.p1.chunkcnt[lane * 4 + j][c];
        int s = vv[0] + vv[1] + vv[2] + vv[3];
        int si = s;
#pragma unroll
        for (int off = 1; off < 64; off <<= 1) {
            int y = __shfl_up(si, off);
            if (lane >= off) si += y;
        }
        int run = si - s;
#pragma unroll
        for (int j = 0; j < 4; ++j) { sm.p1.pfx[lane * 4 + j][c] = run; run += vv[j]; }
        if (lane == 63) sm.p1.tot[c] = si;
    }
    __syncthreads();

    if (arr) {
#pragma unroll
        for (int c = 0; c < 4; ++c) {
            int tc = sm.p1.tot[c];
            int padded = (tc + 127) & ~127;
            ps[c + 1] = ps[c] + padded;
            padc[c] = padded - tc;
        }
        if (u == 0) {   // designated target block writes meta
            if (t < 4) meta[12 + t] = padc[t];
            if (t < NT_TILES) {
                int row = t * 128, cl = 4;
#pragma unroll
                for (int c = 0; c < 4; ++c)
                    if (row >= ps[c] && row < ps[c + 1]) cl = c;
                meta[16 + t] = cl;
            }
        }
        // zero the 512 pad/tail rows: 2 rows per target block
        if (t < 32) {
            int g = u * 2 + (t >> 4);
            int gg = g, c;
            for (c = 0; c < 4; ++c) { if (gg < padc[c]) break; gg -= padc[c]; }
            int row = (c < 4) ? (ps[c + 1] - padc[c] + gg) : (ps[4] + gg);
            short8 z = {};
            *(short8*)(nt_sorted + (long)row * C_DIM + (t & 15) * 8) = z;
        }
    }

    // per-pixel sum of squares: 8 threads per pixel
    int p = t >> 3, sub = t & 7;
    float ss = 0.f;
#pragma unroll
    for (int i = 0; i < 16; ++i) {
        float vv = sm.p1.tile[sub * 16 + i][p];
        ss += vv * vv;
    }
    ss += __shfl_xor(ss, 1);
    ss += __shfl_xor(ss, 2);
    ss += __shfl_xor(ss, 4);
    if (sub == 0) {
        float sc = 1.0f / fmaxf(sqrtf(ss), 1e-12f);
        int n = bb * 4096 + hw0 + p;    // n & 31 == p
        int dst_row;
        if (arr) {
            sc *= TAU_INV_LOG2E;         // fold tau into target rows
            int cme = tseg[n];
            const int* tc32 = tseg + (n & ~31);
            int r = 0;
            for (int j = 0; j < p; ++j) r += (tc32[j] == cme);
            dst_row = ps[cme] + sm.p1.pfx[n >> 5][cme] + r;
        } else {
            dst_row = n;
        }
        sm.p1.sscale[p] = sc;
        sm.p1.sdest[p] = dst_row;
    }
    __syncthreads();

    u16* dst = arr ? nt_sorted : ni_bf;
#pragma unroll
    for (int i = 0; i < 2; ++i) {
        int idx = t + i * 256;
        int px = idx >> 4, kc = idx & 15;
        float sc = sm.p1.sscale[px];
        long drow = sm.p1.sdest[px];
        short8 o;
#pragma unroll
        for (int j = 0; j < 8; ++j)
            o[j] = (short)f2bf(sm.p1.tile[kc * 8 + j][px] * sc);
        *(short8*)(dst + drow * C_DIM + kc * 8) = o;   // 16B stores
    }
}

// ---- Phase 2: GEMM + exp + class-uniform-tile column sums ----
__device__ __forceinline__ void phase2(SMem& sm, int bid, int t,
                                       const u16* __restrict__ ni,
                                       const u16* __restrict__ nt,
                                       const int* __restrict__ piseg,
                                       const int* __restrict__ meta,
                                       float* __restrict__ den,
                                       float* __restrict__ nom) {
    int lane = t & 63, w = t >> 6;
    int bcb = bid & 63;
    int as  = bid >> 6;
    int t0  = as * 8 + (as < 4 ? as : 4);   // tiles: 9,9,9,9,8,8,8,8 (= 68)
    int ntl = 8 + (as < 4 ? 1 : 0);
    int bcol0 = bcb * 128;
    int wr = w >> 1, wc = w & 1;
    int l15 = lane & 15, q = lane >> 4;
    const int* tcls = meta + 16;

    short8 bfrag[4][4];
    int pil[4];
#pragma unroll
    for (int ct = 0; ct < 4; ++ct) {
        int brow = bcol0 + wc * 64 + ct * 16 + l15;
        pil[ct] = piseg[brow];
        const u16* bp = ni + brow * C_DIM + q * 8;
#pragma unroll
        for (int kc = 0; kc < 4; ++kc)
            bfrag[ct][kc] = *(const short8*)(bp + kc * 32);
    }

    float den_l[4] = {0.f, 0.f, 0.f, 0.f};
    float nom_l[4] = {0.f, 0.f, 0.f, 0.f};

    for (int it = 0; it < ntl; ++it) {
        int tile = t0 + it;
        int a0 = tile * 128;
        __syncthreads();
        {
            const uint4* gsrc = (const uint4*)(nt + (long)a0 * C_DIM);
#pragma unroll
            for (int i = 0; i < 8; ++i) {
                int idx = t + i * 256;
                int r = idx >> 4, ch = idx & 15;
                int sw = ch ^ (r & 15);     // XOR swizzle, exact 32KB, no pad
                *(uint4*)(&sm.p2.sA[r * 128 + sw * 8]) = gsrc[idx];
            }
        }
        __syncthreads();

        f32x4 acc[4][4] = {};
#pragma unroll
        for (int kc = 0; kc < 4; ++kc) {
            short8 af[4];
#pragma unroll
            for (int rt = 0; rt < 4; ++rt) {
                int ar = wr * 64 + rt * 16 + l15;
                int sw = (kc * 4 + q) ^ l15;   // ar & 15 == l15
                af[rt] = *(const short8*)(&sm.p2.sA[ar * 128 + sw * 8]);
            }
#pragma unroll
            for (int rt = 0; rt < 4; ++rt)
#pragma unroll
                for (int ct = 0; ct < 4; ++ct)
                    acc[rt][ct] = __builtin_amdgcn_mfma_f32_16x16x32_bf16(
                        af[rt], bfrag[ct][kc], acc[rt][ct], 0, 0, 0);
        }

        int tc = tcls[tile];
        float td[4] = {0.f, 0.f, 0.f, 0.f};
#pragma unroll
        for (int rt = 0; rt < 4; ++rt)
#pragma unroll
            for (int ct = 0; ct < 4; ++ct) {
                f32x4 v = acc[rt][ct];
                float e0 = __builtin_amdgcn_exp2f(v[0]);
                float e1 = __builtin_amdgcn_exp2f(v[1]);
                float e2 = __builtin_amdgcn_exp2f(v[2]);
                float e3 = __builtin_amdgcn_exp2f(v[3]);
                td[ct] += (e0 + e1) + (e2 + e3);
            }
#pragma unroll
        for (int ct = 0; ct < 4; ++ct) {
            den_l[ct] += td[ct];
            nom_l[ct] += (tc == pil[ct]) ? td[ct] : 0.f;
        }
    }

#pragma unroll
    for (int ct = 0; ct < 4; ++ct) {
        float d = den_l[ct], nm = nom_l[ct];
        d += __shfl_xor(d, 16); d += __shfl_xor(d, 32);
        nm += __shfl_xor(nm, 16); nm += __shfl_xor(nm, 32);
        if (lane < 16) {
            int b = bcol0 + wc * 64 + ct * 16 + lane;
            atomicAdd(&den[b], d);
            atomicAdd(&nom[b], nm);
        }
    }
}

// ---- Phase 3: loss = mean(-log(nom/(den+eps))) with pad corrections (256 threads) ----
__device__ __forceinline__ void phase3(SMem& sm, int t,
                                       const float* __restrict__ den,
                                       const float* __restrict__ nom,
                                       const int* __restrict__ piseg,
                                       const int* __restrict__ meta,
                                       float* __restrict__ out) {
    float padcf[4];
#pragma unroll
    for (int c = 0; c < 4; ++c) padcf[c] = (float)meta[12 + c];
    int base = t * 32;
    float s = 0.f;
#pragma unroll
    for (int h = 0; h < 8; ++h) {
        float4 d4 = *(const float4*)(den + base + h * 4);
        float4 n4 = *(const float4*)(nom + base + h * 4);
        int4  p4 = *(const int4*)(piseg + base + h * 4);
        float dd[4] = {d4.x, d4.y, d4.z, d4.w};
        float nn[4] = {n4.x, n4.y, n4.z, n4.w};
        int   pp[4] = {p4.x, p4.y, p4.z, p4.w};
#pragma unroll
        for (int j = 0; j < 4; ++j) {
            float nm = nn[j] - padcf[pp[j]];
            float d = dd[j] - (float)FAKE_ROWS;
            s -= __logf(nm / (d + EPS_DEN));
        }
    }
#pragma unroll
    for (int off = 32; off > 0; off >>= 1) s += __shfl_down(s, off);
    if ((t & 63) == 0) sm.p3.part[t >> 6] = s;
    __syncthreads();
    if (t == 0)
        out[0] = (sm.p3.part[0] + sm.p3.part[1] + sm.p3.part[2] + sm.p3.part[3])
                 * (1.0f / N_PIX);
}

// ================= Cooperative single-launch kernel =================
__global__ __launch_bounds__(256, 2) void fused_k(const float* __restrict__ input,
                                                  const float* __restrict__ target,
                                                  const int* __restrict__ tseg,
                                                  const int* __restrict__ piseg,
                                                  int* __restrict__ meta,
                                                  u16* __restrict__ ni_bf,
                                                  u16* __restrict__ nt_sorted,
                                                  float* __restrict__ den,
                                                  float* __restrict__ nom,
                                                  float* __restrict__ out) {
    cooperative_groups::grid_group grid = cooperative_groups::this_grid();
    __shared__ __align__(16) SMem sm;
    int bid = blockIdx.x, t = threadIdx.x;
    phase1(sm, bid, t, input, target, tseg, meta, ni_bf, nt_sorted, den, nom);
    __threadfence();
    grid.sync();
    phase2(sm, bid, t, ni_bf, nt_sorted, piseg, meta, den, nom);
    __threadfence();
    grid.sync();
    if (bid == 0) phase3(sm, t, den, nom, piseg, meta, out);
}

// ================= Fallback path (2 normal launches) =================
__global__ __launch_bounds__(256) void p1_k(const float* __restrict__ input,
                                            const float* __restrict__ target,
                                            const int* __restrict__ tseg,
                                            int* __restrict__ meta,
                                            u16* __restrict__ ni_bf,
                                            u16* __restrict__ nt_sorted,
                                            float* __restrict__ den,
                                            float* __restrict__ nom) {
    __shared__ __align__(16) SMem sm;
    phase1(sm, blockIdx.x, threadIdx.x, input, target, tseg, meta, ni_bf, nt_sorted, den, nom);
}

__global__ __launch_bounds__(256, 2) void main_loss_k(const u16* __restrict__ ni,
                                                      const u16* __restrict__ nt,
                                                      const int* __restrict__ piseg,
                                                      int* __restrict__ meta,
                                                      float* __restrict__ den,
                                                      float* __restrict__ nom,
                                                      float* __restrict__ out) {
    __shared__ __align__(16) SMem sm;
    __shared__ int is_last;
    int t = threadIdx.x;
    phase2(sm, blockIdx.x, t, ni, nt, piseg, meta, den, nom);
    __threadfence();
    __syncthreads();                 // all this block's atomics complete
    if (t == 0) {
        int tk = atomicAdd(&meta[8], 1);
        is_last = (tk == 511);
    }
    __syncthreads();
    if (is_last) {
        __threadfence();             // acquire: see all blocks' den/nom
        phase3(sm, t, den, nom, piseg, meta, out);
    }
}

extern "C" void kernel_launch(void* const* d_in, const int* in_sizes, int n_in,
                              void* d_out, int out_size, void* d_ws, size_t ws_size,
                              hipStream_t stream) {
    const float* input  = (const float*)d_in[0];
    const float* target = (const float*)d_in[1];
    const int*   iseg   = (const int*)d_in[2];
    const int*   tseg   = (const int*)d_in[3];
    float* out = (float*)d_out;

    char* ws = (char*)d_ws;
    u16* ni_bf     = (u16*)(ws);                    // 8192*128 bf16 = 2 MB
    u16* nt_sorted = (u16*)(ws + 0x200000);         // 8704*128 bf16
    float* den     = (float*)(ws + 0x420000);       // 32 KB
    float* nom     = (float*)(ws + 0x428000);       // 32 KB
    int* meta      = (int*)(ws + 0x430000);         // ticket / pad counts / tile classes

    void* kargs[] = {(void*)&input, (void*)&target, (void*)&tseg, (void*)&iseg,
                     (void*)&meta, (void*)&ni_bf, (void*)&nt_sorted,
                     (void*)&den, (void*)&nom, (void*)&out};
    hipError_t e = hipLaunchCooperativeKernel((void*)fused_k, dim3(512), dim3(256),
                                              kargs, 0, stream);
    if (e != hipSuccess) {
        (void)hipGetLastError();     // clear sticky error, use fallback path
        p1_k<<<512, 256, 0, stream>>>(input, target, tseg, meta, ni_bf, nt_sorted, den, nom);
        main_loss_k<<<512, 256, 0, stream>>>(ni_bf, nt_sorted, iseg, meta, den, nom, out);
    }
}

// Round 7
// 129.967 us; speedup vs baseline: 2.1990x; 2.1990x over previous
//
#include <hip/hip_runtime.h>

#define N_PIX 8192
#define C_DIM 128
#define TAU_INV_LOG2E 20.609929155556622f  // log2(e) / 0.07
#define EPS_DEN 1e-8f
#define NT_TILES 68                        // 4 classes each padded to x128 + tail -> 68 tiles
#define NT_ROWS (NT_TILES * 128)           // 8704
#define FAKE_ROWS (NT_ROWS - N_PIX)        // exactly 512 zero rows; each adds exp2(0)=1 to den

typedef unsigned short u16;
typedef __attribute__((ext_vector_type(8))) short short8;
typedef __attribute__((ext_vector_type(4))) float f32x4;

__device__ __forceinline__ u16 f2bf(float f) {
    unsigned u = __float_as_uint(f);
    return (u16)((u + 0x7fffu + ((u >> 16) & 1u)) >> 16);  // RNE
}

struct P1 {
    float tile[128][33];       // 128 ch x 32 hw, +1 pad  (16896 B)
    float sscale[32];
    int sdest[32];
    int chunkcnt[256][4];      // per-32-pixel-chunk class counts (4096 B)
    int pfx[256][4];           // exclusive prefix per chunk per class (4096 B)
    int tot[4];
};
struct P2 { u16 sA[128 * 128]; };   // XOR-swizzled A-tile, exactly 32768 B
struct P3 { float part[4]; };
union SMem { P1 p1; P2 p2; P3 p3; };  // 32768 B -> 2 blocks/CU

// meta layout (ints): [8] ticket, [12..15] pad_count[4], [16..16+NT_TILES) tile_class

// ---- Phase 1: fused L2-normalize + transpose + (target) inline counting-sort scatter ----
__device__ __forceinline__ void phase1(SMem& sm, int bid, int t,
                                       const float* __restrict__ input,
                                       const float* __restrict__ target,
                                       const int* __restrict__ tseg,
                                       int* __restrict__ meta,
                                       u16* __restrict__ ni_bf,
                                       u16* __restrict__ nt_sorted,
                                       float* __restrict__ den,
                                       float* __restrict__ nom) {
    int lane = t & 63, w = t >> 6;
    int arr = bid >> 8;              // 0 = input, 1 = target
    int u = bid & 255;
    int bb = u >> 7;
    int hw0 = (u & 127) * 32;
    const float* src = (arr ? target : input) + bb * (C_DIM * 4096);

    if (arr == 0) {
        if (t < 32) den[u * 32 + t] = 0.f;
        else if (t < 64) nom[u * 32 + (t - 32)] = 0.f;
        if (bid == 0 && t == 64) meta[8] = 0;   // ticket for last-block loss
    }

    // load 128ch x 32hw fp32 tile (coalesced along hw)
    int c8 = t >> 5, hwl = t & 31;
#pragma unroll
    for (int i = 0; i < 16; ++i) {
        int c = i * 8 + c8;
        sm.p1.tile[c][hwl] = src[c * 4096 + hw0 + hwl];
    }

    int ps[5] = {0, 0, 0, 0, 0};
    int padc[4] = {0, 0, 0, 0};
    if (arr) {
        // redundant per-block histogram of full tseg (32 KB, L2-hot)
        int c0 = 0, c1 = 0, c2 = 0, c3 = 0;
        const int4* ts4 = (const int4*)tseg;
#pragma unroll
        for (int j = 0; j < 8; ++j) {
            int4 x = ts4[t * 8 + j];
            c0 += (x.x == 0) + (x.y == 0) + (x.z == 0) + (x.w == 0);
            c1 += (x.x == 1) + (x.y == 1) + (x.z == 1) + (x.w == 1);
            c2 += (x.x == 2) + (x.y == 2) + (x.z == 2) + (x.w == 2);
            c3 += (x.x == 3) + (x.y == 3) + (x.z == 3) + (x.w == 3);
        }
        sm.p1.chunkcnt[t][0] = c0; sm.p1.chunkcnt[t][1] = c1;
        sm.p1.chunkcnt[t][2] = c2; sm.p1.chunkcnt[t][3] = c3;
    }
    __syncthreads();

    if (arr) {
        // scan: wave w handles class w across 256 chunks
        int c = w;
        int vv[4];
#pragma unroll
        for (int j = 0; j < 4; ++j) vv[j] = sm.p1.chunkcnt[lane * 4 + j][c];
        int s = vv[0] + vv[1] + vv[2] + vv[3];
        int si = s;
#pragma unroll
        for (int off = 1; off < 64; off <<= 1) {
            int y = __shfl_up(si, off);
            if (lane >= off) si += y;
        }
        int run = si - s;
#pragma unroll
        for (int j = 0; j < 4; ++j) { sm.p1.pfx[lane * 4 + j][c] = run; run += vv[j]; }
        if (lane == 63) sm.p1.tot[c] = si;
    }
    __syncthreads();

    if (arr) {
#pragma unroll
        for (int c = 0; c < 4; ++c) {
            int tc = sm.p1.tot[c];
            int padded = (tc + 127) & ~127;
            ps[c + 1] = ps[c] + padded;
            padc[c] = padded - tc;
        }
        if (u == 0) {   // designated target block writes meta
            if (t < 4) meta[12 + t] = padc[t];
            if (t < NT_TILES) {
                int row = t * 128, cl = 4;
#pragma unroll
                for (int c = 0; c < 4; ++c)
                    if (row >= ps[c] && row < ps[c + 1]) cl = c;
                meta[16 + t] = cl;
            }
        }
        // zero the 512 pad/tail rows: 2 rows per target block
        if (t < 32) {
            int g = u * 2 + (t >> 4);
            int gg = g, c;
            for (c = 0; c < 4; ++c) { if (gg < padc[c]) break; gg -= padc[c]; }
            int row = (c < 4) ? (ps[c + 1] - padc[c] + gg) : (ps[4] + gg);
            short8 z = {};
            *(short8*)(nt_sorted + (long)row * C_DIM + (t & 15) * 8) = z;
        }
    }

    // per-pixel sum of squares: 8 threads per pixel
    int p = t >> 3, sub = t & 7;
    float ss = 0.f;
#pragma unroll
    for (int i = 0; i < 16; ++i) {
        float vv = sm.p1.tile[sub * 16 + i][p];
        ss += vv * vv;
    }
    ss += __shfl_xor(ss, 1);
    ss += __shfl_xor(ss, 2);
    ss += __shfl_xor(ss, 4);
    if (sub == 0) {
        float sc = 1.0f / fmaxf(sqrtf(ss), 1e-12f);
        int n = bb * 4096 + hw0 + p;    // n & 31 == p
        int dst_row;
        if (arr) {
            sc *= TAU_INV_LOG2E;         // fold tau into target rows
            int cme = tseg[n];
            const int* tc32 = tseg + (n & ~31);
            int r = 0;
            for (int j = 0; j < p; ++j) r += (tc32[j] == cme);
            dst_row = ps[cme] + sm.p1.pfx[n >> 5][cme] + r;
        } else {
            dst_row = n;
        }
        sm.p1.sscale[p] = sc;
        sm.p1.sdest[p] = dst_row;
    }
    __syncthreads();

    u16* dst = arr ? nt_sorted : ni_bf;
#pragma unroll
    for (int i = 0; i < 2; ++i) {
        int idx = t + i * 256;
        int px = idx >> 4, kc = idx & 15;
        float sc = sm.p1.sscale[px];
        long drow = sm.p1.sdest[px];
        short8 o;
#pragma unroll
        for (int j = 0; j < 8; ++j)
            o[j] = (short)f2bf(sm.p1.tile[kc * 8 + j][px] * sc);
        *(short8*)(dst + drow * C_DIM + kc * 8) = o;   // 16B stores
    }
}

// ---- Phase 2: GEMM + exp + class-uniform-tile column sums ----
__device__ __forceinline__ void phase2(SMem& sm, int bid, int t,
                                       const u16* __restrict__ ni,
                                       const u16* __restrict__ nt,
                                       const int* __restrict__ piseg,
                                       const int* __restrict__ meta,
                                       float* __restrict__ den,
                                       float* __restrict__ nom) {
    int lane = t & 63, w = t >> 6;
    int bcb = bid & 63;
    int as  = bid >> 6;
    int t0  = as * 8 + (as < 4 ? as : 4);   // tiles: 9,9,9,9,8,8,8,8 (= 68)
    int ntl = 8 + (as < 4 ? 1 : 0);
    int bcol0 = bcb * 128;
    int wr = w >> 1, wc = w & 1;
    int l15 = lane & 15, q = lane >> 4;
    const int* tcls = meta + 16;

    short8 bfrag[4][4];
    int pil[4];
#pragma unroll
    for (int ct = 0; ct < 4; ++ct) {
        int brow = bcol0 + wc * 64 + ct * 16 + l15;
        pil[ct] = piseg[brow];
        const u16* bp = ni + brow * C_DIM + q * 8;
#pragma unroll
        for (int kc = 0; kc < 4; ++kc)
            bfrag[ct][kc] = *(const short8*)(bp + kc * 32);
    }

    float den_l[4] = {0.f, 0.f, 0.f, 0.f};
    float nom_l[4] = {0.f, 0.f, 0.f, 0.f};

    for (int it = 0; it < ntl; ++it) {
        int tile = t0 + it;
        int a0 = tile * 128;
        __syncthreads();
        {
            const uint4* gsrc = (const uint4*)(nt + (long)a0 * C_DIM);
#pragma unroll
            for (int i = 0; i < 8; ++i) {
                int idx = t + i * 256;
                int r = idx >> 4, ch = idx & 15;
                int sw = ch ^ (r & 15);     // XOR swizzle, exact 32KB, no pad
                *(uint4*)(&sm.p2.sA[r * 128 + sw * 8]) = gsrc[idx];
            }
        }
        __syncthreads();

        f32x4 acc[4][4] = {};
#pragma unroll
        for (int kc = 0; kc < 4; ++kc) {
            short8 af[4];
#pragma unroll
            for (int rt = 0; rt < 4; ++rt) {
                int ar = wr * 64 + rt * 16 + l15;
                int sw = (kc * 4 + q) ^ l15;   // ar & 15 == l15
                af[rt] = *(const short8*)(&sm.p2.sA[ar * 128 + sw * 8]);
            }
#pragma unroll
            for (int rt = 0; rt < 4; ++rt)
#pragma unroll
                for (int ct = 0; ct < 4; ++ct)
                    acc[rt][ct] = __builtin_amdgcn_mfma_f32_16x16x32_bf16(
                        af[rt], bfrag[ct][kc], acc[rt][ct], 0, 0, 0);
        }

        int tc = tcls[tile];
        float td[4] = {0.f, 0.f, 0.f, 0.f};
#pragma unroll
        for (int rt = 0; rt < 4; ++rt)
#pragma unroll
            for (int ct = 0; ct < 4; ++ct) {
                f32x4 v = acc[rt][ct];
                float e0 = __builtin_amdgcn_exp2f(v[0]);
                float e1 = __builtin_amdgcn_exp2f(v[1]);
                float e2 = __builtin_amdgcn_exp2f(v[2]);
                float e3 = __builtin_amdgcn_exp2f(v[3]);
                td[ct] += (e0 + e1) + (e2 + e3);
            }
#pragma unroll
        for (int ct = 0; ct < 4; ++ct) {
            den_l[ct] += td[ct];
            nom_l[ct] += (tc == pil[ct]) ? td[ct] : 0.f;
        }
    }

#pragma unroll
    for (int ct = 0; ct < 4; ++ct) {
        float d = den_l[ct], nm = nom_l[ct];
        d += __shfl_xor(d, 16); d += __shfl_xor(d, 32);
        nm += __shfl_xor(nm, 16); nm += __shfl_xor(nm, 32);
        if (lane < 16) {
            int b = bcol0 + wc * 64 + ct * 16 + lane;
            atomicAdd(&den[b], d);
            atomicAdd(&nom[b], nm);
        }
    }
}

// ---- Phase 3: loss = mean(-log(nom/(den+eps))); den/nom read with agent-scope atomics ----
__device__ __forceinline__ void phase3(SMem& sm, int t,
                                       const float* __restrict__ den,
                                       const float* __restrict__ nom,
                                       const int* __restrict__ piseg,
                                       const int* __restrict__ meta,
                                       float* __restrict__ out) {
    float padcf[4];
#pragma unroll
    for (int c = 0; c < 4; ++c) padcf[c] = (float)meta[12 + c];
    int base = t * 32;
    float s = 0.f;
#pragma unroll
    for (int j = 0; j < 32; ++j) {
        float d = __hip_atomic_load(den + base + j, __ATOMIC_RELAXED, __HIP_MEMORY_SCOPE_AGENT);
        float nmv = __hip_atomic_load(nom + base + j, __ATOMIC_RELAXED, __HIP_MEMORY_SCOPE_AGENT);
        int pcls = piseg[base + j];
        float nm = nmv - padcf[pcls];
        float dd = d - (float)FAKE_ROWS;
        s -= __logf(nm / (dd + EPS_DEN));
    }
#pragma unroll
    for (int off = 32; off > 0; off >>= 1) s += __shfl_down(s, off);
    if ((t & 63) == 0) sm.p3.part[t >> 6] = s;
    __syncthreads();
    if (t == 0)
        out[0] = (sm.p3.part[0] + sm.p3.part[1] + sm.p3.part[2] + sm.p3.part[3])
                 * (1.0f / N_PIX);
}

// ================= Node 1: phase 1 =================
__global__ __launch_bounds__(256) void p1_k(const float* __restrict__ input,
                                            const float* __restrict__ target,
                                            const int* __restrict__ tseg,
                                            int* __restrict__ meta,
                                            u16* __restrict__ ni_bf,
                                            u16* __restrict__ nt_sorted,
                                            float* __restrict__ den,
                                            float* __restrict__ nom) {
    __shared__ __align__(16) SMem sm;
    phase1(sm, blockIdx.x, threadIdx.x, input, target, tseg, meta, ni_bf, nt_sorted, den, nom);
}

// ================= Node 2: phase 2 + last-block phase 3 =================
__global__ __launch_bounds__(256, 2) void main_loss_k(const u16* __restrict__ ni,
                                                      const u16* __restrict__ nt,
                                                      const int* __restrict__ piseg,
                                                      int* __restrict__ meta,
                                                      float* __restrict__ den,
                                                      float* __restrict__ nom,
                                                      float* __restrict__ out) {
    __shared__ __align__(16) SMem sm;
    __shared__ int is_last;
    int t = threadIdx.x;
    phase2(sm, blockIdx.x, t, ni, nt, piseg, meta, den, nom);
    __threadfence();                 // release: this block's den/nom atomics
    __syncthreads();
    if (t == 0) {
        int tk = atomicAdd(&meta[8], 1);
        is_last = (tk == 511);
    }
    __syncthreads();
    if (is_last) {
        __threadfence();             // acquire: see all blocks' den/nom
        phase3(sm, t, den, nom, piseg, meta, out);
    }
}

extern "C" void kernel_launch(void* const* d_in, const int* in_sizes, int n_in,
                              void* d_out, int out_size, void* d_ws, size_t ws_size,
                              hipStream_t stream) {
    const float* input  = (const float*)d_in[0];
    const float* target = (const float*)d_in[1];
    const int*   iseg   = (const int*)d_in[2];
    const int*   tseg   = (const int*)d_in[3];
    float* out = (float*)d_out;

    char* ws = (char*)d_ws;
    u16* ni_bf     = (u16*)(ws);                    // 8192*128 bf16 = 2 MB
    u16* nt_sorted = (u16*)(ws + 0x200000);         // 8704*128 bf16
    float* den     = (float*)(ws + 0x420000);       // 32 KB
    float* nom     = (float*)(ws + 0x428000);       // 32 KB
    int* meta      = (int*)(ws + 0x430000);         // ticket / pad counts / tile classes

    p1_k<<<512, 256, 0, stream>>>(input, target, tseg, meta, ni_bf, nt_sorted, den, nom);
    main_loss_k<<<512, 256, 0, stream>>>(ni_bf, nt_sorted, iseg, meta, den, nom, out);
}

// Round 8
// 105.577 us; speedup vs baseline: 2.7070x; 1.2310x over previous
//
#include <hip/hip_runtime.h>

#define N_PIX 8192
#define C_DIM 128
#define TAU_INV_LOG2E 20.609929155556622f  // log2(e) / 0.07
#define EPS_DEN 1e-8f
#define NT_TILES 68                        // 4 classes each padded to x128 + tail -> 68 tiles
#define NT_ROWS (NT_TILES * 128)           // 8704
#define FAKE_ROWS (NT_ROWS - N_PIX)        // exactly 512 zero rows; each adds exp2(0)=1 to den

typedef unsigned short u16;
typedef __attribute__((ext_vector_type(8))) short short8;
typedef __attribute__((ext_vector_type(4))) float f32x4;

__device__ __forceinline__ u16 f2bf(float f) {
    unsigned u = __float_as_uint(f);
    return (u16)((u + 0x7fffu + ((u >> 16) & 1u)) >> 16);  // RNE
}

struct P1 {
    float tile[128][33];       // 128 ch x 32 hw, +1 pad  (16896 B)
    float sscale[32];
    int sdest[32];
    int chunkcnt[256][4];      // per-32-pixel-chunk class counts (4096 B)
    int pfx[256][4];           // exclusive prefix per chunk per class (4096 B)
    int tot[4];
};
struct P2 { u16 sA[128 * 128]; };   // XOR-swizzled A-tile, exactly 32768 B
struct P3 { float part[4]; };
union SMem { P1 p1; P2 p2; P3 p3; };  // 32768 B -> 2 blocks/CU

// meta layout (ints): [0..7] leaf tickets (by as-group), [8] root ticket,
//                     [12..15] pad_count[4], [16..16+NT_TILES) tile_class

// ---- Phase 1: fused L2-normalize + transpose + (target) inline counting-sort scatter ----
__device__ __forceinline__ void phase1(SMem& sm, int bid, int t,
                                       const float* __restrict__ input,
                                       const float* __restrict__ target,
                                       const int* __restrict__ tseg,
                                       int* __restrict__ meta,
                                       u16* __restrict__ ni_bf,
                                       u16* __restrict__ nt_sorted,
                                       float* __restrict__ den,
                                       float* __restrict__ nom) {
    int lane = t & 63, w = t >> 6;
    int arr = bid >> 8;              // 0 = input, 1 = target
    int u = bid & 255;
    int bb = u >> 7;
    int hw0 = (u & 127) * 32;
    const float* src = (arr ? target : input) + bb * (C_DIM * 4096);

    if (arr == 0) {
        if (t < 32) den[u * 32 + t] = 0.f;
        else if (t < 64) nom[u * 32 + (t - 32)] = 0.f;
        if (bid == 0 && t >= 64 && t < 73) meta[t - 64] = 0;   // 8 leaf + 1 root tickets
    }

    // load 128ch x 32hw fp32 tile (coalesced along hw)
    int c8 = t >> 5, hwl = t & 31;
#pragma unroll
    for (int i = 0; i < 16; ++i) {
        int c = i * 8 + c8;
        sm.p1.tile[c][hwl] = src[c * 4096 + hw0 + hwl];
    }

    int ps[5] = {0, 0, 0, 0, 0};
    int padc[4] = {0, 0, 0, 0};
    if (arr) {
        // redundant per-block histogram of full tseg (32 KB, L2-hot)
        int c0 = 0, c1 = 0, c2 = 0, c3 = 0;
        const int4* ts4 = (const int4*)tseg;
#pragma unroll
        for (int j = 0; j < 8; ++j) {
            int4 x = ts4[t * 8 + j];
            c0 += (x.x == 0) + (x.y == 0) + (x.z == 0) + (x.w == 0);
            c1 += (x.x == 1) + (x.y == 1) + (x.z == 1) + (x.w == 1);
            c2 += (x.x == 2) + (x.y == 2) + (x.z == 2) + (x.w == 2);
            c3 += (x.x == 3) + (x.y == 3) + (x.z == 3) + (x.w == 3);
        }
        sm.p1.chunkcnt[t][0] = c0; sm.p1.chunkcnt[t][1] = c1;
        sm.p1.chunkcnt[t][2] = c2; sm.p1.chunkcnt[t][3] = c3;
    }
    __syncthreads();

    if (arr) {
        // scan: wave w handles class w across 256 chunks
        int c = w;
        int vv[4];
#pragma unroll
        for (int j = 0; j < 4; ++j) vv[j] = sm.p1.chunkcnt[lane * 4 + j][c];
        int s = vv[0] + vv[1] + vv[2] + vv[3];
        int si = s;
#pragma unroll
        for (int off = 1; off < 64; off <<= 1) {
            int y = __shfl_up(si, off);
            if (lane >= off) si += y;
        }
        int run = si - s;
#pragma unroll
        for (int j = 0; j < 4; ++j) { sm.p1.pfx[lane * 4 + j][c] = run; run += vv[j]; }
        if (lane == 63) sm.p1.tot[c] = si;
    }
    __syncthreads();

    if (arr) {
#pragma unroll
        for (int c = 0; c < 4; ++c) {
            int tc = sm.p1.tot[c];
            int padded = (tc + 127) & ~127;
            ps[c + 1] = ps[c] + padded;
            padc[c] = padded - tc;
        }
        if (u == 0) {   // designated target block writes meta
            if (t < 4) meta[12 + t] = padc[t];
            if (t < NT_TILES) {
                int row = t * 128, cl = 4;
#pragma unroll
                for (int c = 0; c < 4; ++c)
                    if (row >= ps[c] && row < ps[c + 1]) cl = c;
                meta[16 + t] = cl;
            }
        }
        // zero the 512 pad/tail rows: 2 rows per target block
        if (t < 32) {
            int g = u * 2 + (t >> 4);
            int gg = g, c;
            for (c = 0; c < 4; ++c) { if (gg < padc[c]) break; gg -= padc[c]; }
            int row = (c < 4) ? (ps[c + 1] - padc[c] + gg) : (ps[4] + gg);
            short8 z = {};
            *(short8*)(nt_sorted + (long)row * C_DIM + (t & 15) * 8) = z;
        }
    }

    // per-pixel sum of squares: 8 threads per pixel
    int p = t >> 3, sub = t & 7;
    float ss = 0.f;
#pragma unroll
    for (int i = 0; i < 16; ++i) {
        float vv = sm.p1.tile[sub * 16 + i][p];
        ss += vv * vv;
    }
    ss += __shfl_xor(ss, 1);
    ss += __shfl_xor(ss, 2);
    ss += __shfl_xor(ss, 4);
    if (sub == 0) {
        float sc = 1.0f / fmaxf(sqrtf(ss), 1e-12f);
        int n = bb * 4096 + hw0 + p;    // n & 31 == p
        int dst_row;
        if (arr) {
            sc *= TAU_INV_LOG2E;         // fold tau into target rows
            int cme = tseg[n];
            const int* tc32 = tseg + (n & ~31);
            int r = 0;
            for (int j = 0; j < p; ++j) r += (tc32[j] == cme);
            dst_row = ps[cme] + sm.p1.pfx[n >> 5][cme] + r;
        } else {
            dst_row = n;
        }
        sm.p1.sscale[p] = sc;
        sm.p1.sdest[p] = dst_row;
    }
    __syncthreads();

    u16* dst = arr ? nt_sorted : ni_bf;
#pragma unroll
    for (int i = 0; i < 2; ++i) {
        int idx = t + i * 256;
        int px = idx >> 4, kc = idx & 15;
        float sc = sm.p1.sscale[px];
        long drow = sm.p1.sdest[px];
        short8 o;
#pragma unroll
        for (int j = 0; j < 8; ++j)
            o[j] = (short)f2bf(sm.p1.tile[kc * 8 + j][px] * sc);
        *(short8*)(dst + drow * C_DIM + kc * 8) = o;   // 16B stores
    }
}

// ---- Phase 2: GEMM + exp + class-uniform-tile column sums ----
__device__ __forceinline__ void phase2(SMem& sm, int bid, int t,
                                       const u16* __restrict__ ni,
                                       const u16* __restrict__ nt,
                                       const int* __restrict__ piseg,
                                       const int* __restrict__ meta,
                                       float* __restrict__ den,
                                       float* __restrict__ nom) {
    int lane = t & 63, w = t >> 6;
    int bcb = bid & 63;
    int as  = bid >> 6;
    int t0  = as * 8 + (as < 4 ? as : 4);   // tiles: 9,9,9,9,8,8,8,8 (= 68)
    int ntl = 8 + (as < 4 ? 1 : 0);
    int bcol0 = bcb * 128;
    int wr = w >> 1, wc = w & 1;
    int l15 = lane & 15, q = lane >> 4;
    const int* tcls = meta + 16;

    short8 bfrag[4][4];
    int pil[4];
#pragma unroll
    for (int ct = 0; ct < 4; ++ct) {
        int brow = bcol0 + wc * 64 + ct * 16 + l15;
        pil[ct] = piseg[brow];
        const u16* bp = ni + brow * C_DIM + q * 8;
#pragma unroll
        for (int kc = 0; kc < 4; ++kc)
            bfrag[ct][kc] = *(const short8*)(bp + kc * 32);
    }

    float den_l[4] = {0.f, 0.f, 0.f, 0.f};
    float nom_l[4] = {0.f, 0.f, 0.f, 0.f};

    for (int it = 0; it < ntl; ++it) {
        int tile = t0 + it;
        int a0 = tile * 128;
        __syncthreads();
        {
            const uint4* gsrc = (const uint4*)(nt + (long)a0 * C_DIM);
#pragma unroll
            for (int i = 0; i < 8; ++i) {
                int idx = t + i * 256;
                int r = idx >> 4, ch = idx & 15;
                int sw = ch ^ (r & 15);     // XOR swizzle, exact 32KB, no pad
                *(uint4*)(&sm.p2.sA[r * 128 + sw * 8]) = gsrc[idx];
            }
        }
        __syncthreads();

        f32x4 acc[4][4] = {};
#pragma unroll
        for (int kc = 0; kc < 4; ++kc) {
            short8 af[4];
#pragma unroll
            for (int rt = 0; rt < 4; ++rt) {
                int ar = wr * 64 + rt * 16 + l15;
                int sw = (kc * 4 + q) ^ l15;   // ar & 15 == l15
                af[rt] = *(const short8*)(&sm.p2.sA[ar * 128 + sw * 8]);
            }
#pragma unroll
            for (int rt = 0; rt < 4; ++rt)
#pragma unroll
                for (int ct = 0; ct < 4; ++ct)
                    acc[rt][ct] = __builtin_amdgcn_mfma_f32_16x16x32_bf16(
                        af[rt], bfrag[ct][kc], acc[rt][ct], 0, 0, 0);
        }

        int tc = tcls[tile];
        float td[4] = {0.f, 0.f, 0.f, 0.f};
#pragma unroll
        for (int rt = 0; rt < 4; ++rt)
#pragma unroll
            for (int ct = 0; ct < 4; ++ct) {
                f32x4 v = acc[rt][ct];
                float e0 = __builtin_amdgcn_exp2f(v[0]);
                float e1 = __builtin_amdgcn_exp2f(v[1]);
                float e2 = __builtin_amdgcn_exp2f(v[2]);
                float e3 = __builtin_amdgcn_exp2f(v[3]);
                td[ct] += (e0 + e1) + (e2 + e3);
            }
#pragma unroll
        for (int ct = 0; ct < 4; ++ct) {
            den_l[ct] += td[ct];
            nom_l[ct] += (tc == pil[ct]) ? td[ct] : 0.f;
        }
    }

#pragma unroll
    for (int ct = 0; ct < 4; ++ct) {
        float d = den_l[ct], nm = nom_l[ct];
        d += __shfl_xor(d, 16); d += __shfl_xor(d, 32);
        nm += __shfl_xor(nm, 16); nm += __shfl_xor(nm, 32);
        if (lane < 16) {
            int b = bcol0 + wc * 64 + ct * 16 + lane;
            atomicAdd(&den[b], d);
            atomicAdd(&nom[b], nm);
        }
    }
}

// ---- Phase 3: loss = mean(-log(nom/(den+eps))); den/nom read with agent-scope atomics ----
__device__ __forceinline__ void phase3(SMem& sm, int t,
                                       const float* __restrict__ den,
                                       const float* __restrict__ nom,
                                       const int* __restrict__ piseg,
                                       const int* __restrict__ meta,
                                       float* __restrict__ out) {
    float padcf[4];
#pragma unroll
    for (int c = 0; c < 4; ++c) padcf[c] = (float)meta[12 + c];
    int base = t * 32;
    float s = 0.f;
#pragma unroll
    for (int h = 0; h < 4; ++h) {
        // batch 8 independent pairs so the atomic loads pipeline
        float dv[8], nv[8];
        int pc[8];
#pragma unroll
        for (int j = 0; j < 8; ++j) {
            int i = base + h * 8 + j;
            dv[j] = __hip_atomic_load(den + i, __ATOMIC_RELAXED, __HIP_MEMORY_SCOPE_AGENT);
            nv[j] = __hip_atomic_load(nom + i, __ATOMIC_RELAXED, __HIP_MEMORY_SCOPE_AGENT);
            pc[j] = piseg[i];
        }
#pragma unroll
        for (int j = 0; j < 8; ++j) {
            float nm = nv[j] - padcf[pc[j]];
            float dd = dv[j] - (float)FAKE_ROWS;
            s -= __logf(nm / (dd + EPS_DEN));
        }
    }
#pragma unroll
    for (int off = 32; off > 0; off >>= 1) s += __shfl_down(s, off);
    if ((t & 63) == 0) sm.p3.part[t >> 6] = s;
    __syncthreads();
    if (t == 0)
        out[0] = (sm.p3.part[0] + sm.p3.part[1] + sm.p3.part[2] + sm.p3.part[3])
                 * (1.0f / N_PIX);
}

// ================= Node 1: phase 1 =================
__global__ __launch_bounds__(256) void p1_k(const float* __restrict__ input,
                                            const float* __restrict__ target,
                                            const int* __restrict__ tseg,
                                            int* __restrict__ meta,
                                            u16* __restrict__ ni_bf,
                                            u16* __restrict__ nt_sorted,
                                            float* __restrict__ den,
                                            float* __restrict__ nom) {
    __shared__ __align__(16) SMem sm;
    phase1(sm, blockIdx.x, threadIdx.x, input, target, tseg, meta, ni_bf, nt_sorted, den, nom);
}

// ================= Node 2: phase 2 + last-block phase 3 (fence-free ticket tree) ============
// den/nom are only ever written with device-scope atomics (coherent by construction).
// __syncthreads() drains vmcnt(0) (compiler-emitted before s_barrier), so after the barrier
// every atomicAdd from this block has reached the coherence point -> a relaxed ticket
// suffices; NO __threadfence() (which would emit a per-block L2 writeback, ~60us total).
__global__ __launch_bounds__(256, 2) void main_loss_k(const u16* __restrict__ ni,
                                                      const u16* __restrict__ nt,
                                                      const int* __restrict__ piseg,
                                                      int* __restrict__ meta,
                                                      float* __restrict__ den,
                                                      float* __restrict__ nom,
                                                      float* __restrict__ out) {
    __shared__ __align__(16) SMem sm;
    __shared__ int is_last;
    int t = threadIdx.x;
    phase2(sm, blockIdx.x, t, ni, nt, piseg, meta, den, nom);
    __syncthreads();                 // drains vmcnt -> this block's atomics are complete
    if (t == 0) {
        int leaf = blockIdx.x >> 6;                       // 8 groups of 64 blocks
        int lk = atomicAdd(&meta[leaf], 1);
        int last = 0;
        if (lk == 63) {                                    // last block of this leaf
            int rk = atomicAdd(&meta[8], 1);
            last = (rk == 7);                              // last leaf overall
        }
        is_last = last;
    }
    __syncthreads();
    if (is_last) phase3(sm, t, den, nom, piseg, meta, out);
}

extern "C" void kernel_launch(void* const* d_in, const int* in_sizes, int n_in,
                              void* d_out, int out_size, void* d_ws, size_t ws_size,
                              hipStream_t stream) {
    const float* input  = (const float*)d_in[0];
    const float* target = (const float*)d_in[1];
    const int*   iseg   = (const int*)d_in[2];
    const int*   tseg   = (const int*)d_in[3];
    float* out = (float*)d_out;

    char* ws = (char*)d_ws;
    u16* ni_bf     = (u16*)(ws);                    // 8192*128 bf16 = 2 MB
    u16* nt_sorted = (u16*)(ws + 0x200000);         // 8704*128 bf16
    float* den     = (float*)(ws + 0x420000);       // 32 KB
    float* nom     = (float*)(ws + 0x428000);       // 32 KB
    int* meta      = (int*)(ws + 0x430000);         // tickets / pad counts / tile classes

    p1_k<<<512, 256, 0, stream>>>(input, target, tseg, meta, ni_bf, nt_sorted, den, nom);
    main_loss_k<<<512, 256, 0, stream>>>(ni_bf, nt_sorted, iseg, meta, den, nom, out);
}